// Round 7
// baseline (64388.818 us; speedup 1.0000x reference)
//
#include <hip/hip_runtime.h>
#include <math.h>

#define SD   2048
#define HD   1024
#define TPB  512    // 8 waves
#define NBLK 256    // one block per CU

// ---- ws layout (float offsets); first 4KB = barrier flags ----
#define E_OFF   1024
#define H0_OFF  3072
#define INP_OFF 4096
#define X_OFF   5120
#define M_OFF   8192                     // M[1024][2048] = comb_w[:,1024:] @ enc^T
#define M_SZ    (HD * SD)
#define XH_OFF  (M_OFF + M_SZ)           // xh[(SD+1)][HD] history (MODE2)
#define XH_SZ   ((SD + 1) * HD)
#define WS_NEED_M  ((size_t)(M_OFF + M_SZ + HD) * 4)
#define WS_NEED_XH ((size_t)(XH_OFF + XH_SZ) * 4)

typedef unsigned long long u64;

// coherent accessors (sc1, bypass L1/L2; no cache-nuking fences)
__device__ __forceinline__ float ldcf(const float* p) {
  return __hip_atomic_load(p, __ATOMIC_RELAXED, __HIP_MEMORY_SCOPE_AGENT);
}
__device__ __forceinline__ float2 ldc2(const float* p) {
  u64 u = __hip_atomic_load((const u64*)p, __ATOMIC_RELAXED, __HIP_MEMORY_SCOPE_AGENT);
  union { u64 u; float2 f; } c; c.u = u; return c.f;
}
__device__ __forceinline__ void stcf(float* p, float v) {
  __hip_atomic_store(p, v, __ATOMIC_RELAXED, __HIP_MEMORY_SCOPE_AGENT);
}
__device__ __forceinline__ unsigned ldb(const unsigned* p) {
  return __hip_atomic_load(p, __ATOMIC_RELAXED, __HIP_MEMORY_SCOPE_AGENT);
}
__device__ __forceinline__ void stb(unsigned* p, unsigned v) {
  __hip_atomic_store(p, v, __ATOMIC_RELAXED, __HIP_MEMORY_SCOPE_AGENT);
}

__device__ __forceinline__ float dot4(float4 a, float4 b) {
  return a.x * b.x + a.y * b.y + a.z * b.z + a.w * b.w;
}
__device__ __forceinline__ float wred(float v) {
  v += __shfl_xor(v, 32, 64); v += __shfl_xor(v, 16, 64);
  v += __shfl_xor(v, 8, 64);  v += __shfl_xor(v, 4, 64);
  v += __shfl_xor(v, 2, 64);  v += __shfl_xor(v, 1, 64);
  return v;
}
__device__ __forceinline__ float sigm(float x) { return 1.0f / (1.0f + __expf(-x)); }

// arrive: syncthreads drains this block's sc1 stores, then publish epoch flag
__device__ __forceinline__ void bar_arrive(unsigned* bar, unsigned ep) {
  __syncthreads();
  if (threadIdx.x == 0) stb(bar + blockIdx.x, ep);
}
// wait+stage: wave 0 flat-polls ALL 256 flags (1KB/iter, latency-paced);
// on detection it stages the fresh vector ws->LDS itself; one syncthreads
// releases the block. Removes the master->replica hops of round 5.
__device__ __forceinline__ void bar_wait_stage(unsigned* bar, unsigned ep,
                                               float* d0, const float* s0, int n0) {
  if (threadIdx.x < 64) {
    const int lane = threadIdx.x;
    unsigned m;
    do {
      unsigned a = ldb(bar + lane),       b = ldb(bar + 64 + lane);
      unsigned c = ldb(bar + 128 + lane), d = ldb(bar + 192 + lane);
      unsigned ab = a < b ? a : b, cd = c < d ? c : d;
      m = ab < cd ? ab : cd;
#pragma unroll
      for (int s = 32; s; s >>= 1) {
        unsigned o = (unsigned)__shfl_xor((int)m, s, 64);
        m = m < o ? m : o;
      }
    } while (m < ep);
    if (d0)
      for (int i = lane; i < n0; i += 64)
        *(float2*)(d0 + 2 * i) = ldc2(s0 + 2 * i);
  }
  __syncthreads();
}

// 8-wave classifier (MODE1 in-loop / final)
__device__ void classifier8(const float* smx, const float* __restrict__ lin1_w,
                            const float* __restrict__ lin1_b,
                            const float* __restrict__ lin2_w,
                            const float* __restrict__ lin2_b,
                            float* __restrict__ out2, float* scratch) {
  const int tid = threadIdx.x, wid = tid >> 6, lane = tid & 63;
#pragma unroll
  for (int oi = 0; oi < 8; ++oi) {
    const int o = wid * 8 + oi;
    float acc = 0.f;
#pragma unroll
    for (int p = 0; p < 4; ++p)
      acc += dot4(*(const float4*)(lin1_w + (size_t)o * HD + p * 256 + lane * 4),
                  *(const float4*)(smx + p * 256 + lane * 4));
    acc = wred(acc);
    if (lane == 0) scratch[o] = fmaxf(acc + lin1_b[o], 0.f);
  }
  __syncthreads();
  if (tid < 64) {
    float hv = scratch[tid];
    float r0 = wred(hv * lin2_w[tid]);
    float r1 = wred(hv * lin2_w[64 + tid]);
    if (tid == 0) {
      float l0 = r0 + lin2_b[0], l1 = r1 + lin2_b[1];
      float m = fmaxf(l0, l1);
      float e0 = __expf(l0 - m), e1 = __expf(l1 - m);
      float inv = 1.f / (e0 + e1);
      out2[0] = e0 * inv; out2[1] = e1 * inv;
    }
  }
  __syncthreads();
}

template <int MODE>   // 2: xh history + epilogue classifier; 1: in-loop classifier
__global__ void __launch_bounds__(TPB, 2)
decoder_kernel(const float* __restrict__ enc, const float* __restrict__ attn_w,
               const float* __restrict__ attn_b, const float* __restrict__ comb_w,
               const float* __restrict__ comb_b, const float* __restrict__ w_ih,
               const float* __restrict__ w_hh, const float* __restrict__ b_ih,
               const float* __restrict__ b_hh, const float* __restrict__ lin1_w,
               const float* __restrict__ lin1_b, const float* __restrict__ lin2_w,
               const float* __restrict__ lin2_b, const float* __restrict__ hidden,
               const float* __restrict__ cell, float* __restrict__ out,
               float* __restrict__ ws) {
  __shared__ __align__(16) float lds_x[HD];
  __shared__ __align__(16) float lds_h0[HD];
  __shared__ __align__(16) float lds_e[SD];
  __shared__ __align__(16) float lds_v[HD];
  __shared__ __align__(16) float lds_big[8 * HD];
  __shared__ float sg[16], bs0[16], bs1[16], scb[4], sc0[4], sc1_[4];

  const int tid = threadIdx.x, wid = tid >> 6, lane = tid & 63;
  const int bid = blockIdx.x;
  unsigned* bar = (unsigned*)ws;
  unsigned ep = 0;

  // ================= prologue: M = comb_w[:,1024:] @ enc^T =================
  {
    const int j0 = (bid >> 3) * 32, i0 = (bid & 7) * 256;
    float4 cw0[4], cw1[4], cw2[4], cw3[4];
#pragma unroll
    for (int p = 0; p < 4; ++p) {
      cw0[p] = *(const float4*)(comb_w + (size_t)(j0 + wid * 4 + 0) * 2048 + 1024 + p * 256 + lane * 4);
      cw1[p] = *(const float4*)(comb_w + (size_t)(j0 + wid * 4 + 1) * 2048 + 1024 + p * 256 + lane * 4);
      cw2[p] = *(const float4*)(comb_w + (size_t)(j0 + wid * 4 + 2) * 2048 + 1024 + p * 256 + lane * 4);
      cw3[p] = *(const float4*)(comb_w + (size_t)(j0 + wid * 4 + 3) * 2048 + 1024 + p * 256 + lane * 4);
    }
    for (int ib = 0; ib < 32; ++ib) {
      const int rl = tid >> 6, cs = (tid & 63) * 16;
      const float* src = enc + (size_t)(i0 + ib * 8 + rl) * HD + cs;
#pragma unroll
      for (int q = 0; q < 4; ++q)
        *(float4*)(lds_big + rl * HD + cs + q * 4) = *(const float4*)(src + q * 4);
      __syncthreads();
#pragma unroll 1
      for (int ii = 0; ii < 8; ++ii) {
        float a0 = 0.f, a1 = 0.f, a2 = 0.f, a3 = 0.f;
#pragma unroll
        for (int p = 0; p < 4; ++p) {
          float4 e4 = *(const float4*)(lds_big + ii * HD + p * 256 + lane * 4);
          a0 += dot4(cw0[p], e4); a1 += dot4(cw1[p], e4);
          a2 += dot4(cw2[p], e4); a3 += dot4(cw3[p], e4);
        }
        a0 = wred(a0); a1 = wred(a1); a2 = wred(a2); a3 = wred(a3);
        if (lane == 0) {
          const int i = i0 + ib * 8 + ii;
          stcf(ws + M_OFF + (size_t)(j0 + wid * 4 + 0) * SD + i, a0);
          stcf(ws + M_OFF + (size_t)(j0 + wid * 4 + 1) * SD + i, a1);
          stcf(ws + M_OFF + (size_t)(j0 + wid * 4 + 2) * SD + i, a2);
          stcf(ws + M_OFF + (size_t)(j0 + wid * 4 + 3) * SD + i, a3);
        }
      }
      __syncthreads();
    }
  }
  // recurrent-state init
  float* xrow0 = (MODE == 2) ? (ws + XH_OFF) : (ws + X_OFF);
  if (bid == 0) { stcf(xrow0 + tid, 0.f); stcf(xrow0 + 512 + tid, 0.f); }
  *(float2*)(lds_h0 + tid * 2) = *(const float2*)(hidden + tid * 2);
  if (tid < 16) {
    const int g = tid & 3, k = bid * 4 + (tid >> 2);
    bs0[tid] = b_ih[g * HD + k] + b_hh[g * HD + k];
    bs1[tid] = b_ih[4 * HD + g * HD + k] + b_hh[4 * HD + g * HD + k];
  }
  if (tid < 4) {
    scb[tid]  = comb_b[bid * 4 + tid];
    sc0[tid]  = cell[bid * 4 + tid];
    sc1_[tid] = cell[HD + bid * 4 + tid];
  }
  ++ep; bar_arrive(bar, ep);
  bar_wait_stage(bar, ep, nullptr, nullptr, 0);   // M + x(0) visible

  // ================= pin per-wave weight rows =================
  const int gw = bid * 8 + wid;                 // attn row
  float4 wa[8]; float ab = attn_b[gw];
#pragma unroll
  for (int p = 0; p < 8; ++p)
    wa[p] = *(const float4*)(attn_w + (size_t)gw * 2048 + p * 256 + lane * 4);
  const int jB = bid * 4 + (wid >> 1);          // comb/M row (2 waves redundant)
  float4 wxp[4], wmp[8];
#pragma unroll
  for (int p = 0; p < 4; ++p)
    wxp[p] = *(const float4*)(comb_w + (size_t)jB * 2048 + p * 256 + lane * 4);
#pragma unroll
  for (int p = 0; p < 8; ++p)
    wmp[p] = *(const float4*)(ws + M_OFF + (size_t)jB * SD + p * 256 + lane * 4);
  const int kC = bid * 4 + (wid >> 1), gb = (wid & 1) * 2;
  float4 wi0A[4], wi0B[4], wh0A[4], wh0B[4], wi1A[4], wi1B[4], wh1A[4], wh1B[4];
#pragma unroll
  for (int p = 0; p < 4; ++p) {
    wi0A[p] = *(const float4*)(w_ih + (size_t)((gb + 0) * HD + kC) * HD + p * 256 + lane * 4);
    wi0B[p] = *(const float4*)(w_ih + (size_t)((gb + 1) * HD + kC) * HD + p * 256 + lane * 4);
    wh0A[p] = *(const float4*)(w_hh + (size_t)((gb + 0) * HD + kC) * HD + p * 256 + lane * 4);
    wh0B[p] = *(const float4*)(w_hh + (size_t)((gb + 1) * HD + kC) * HD + p * 256 + lane * 4);
    wi1A[p] = *(const float4*)(w_ih + (size_t)4 * HD * HD + (size_t)((gb + 0) * HD + kC) * HD + p * 256 + lane * 4);
    wi1B[p] = *(const float4*)(w_ih + (size_t)4 * HD * HD + (size_t)((gb + 1) * HD + kC) * HD + p * 256 + lane * 4);
    wh1A[p] = *(const float4*)(w_hh + (size_t)4 * HD * HD + (size_t)((gb + 0) * HD + kC) * HD + p * 256 + lane * 4);
    wh1B[p] = *(const float4*)(w_hh + (size_t)4 * HD * HD + (size_t)((gb + 1) * HD + kC) * HD + p * 256 + lane * 4);
  }

  // ================= main loop: 4 flag-phases/step =================
  for (int t = 0; t < SD; ++t) {
    const float* xrow_ld = (MODE == 2) ? (ws + XH_OFF + (size_t)t * HD) : (ws + X_OFF);
    float* xrow_st = (MODE == 2) ? (ws + XH_OFF + (size_t)(t + 1) * HD) : (ws + X_OFF);

    // ---- A: wait x(t); e[gw] = exp(attn_row . [x;h0] + b) ----
    bar_wait_stage(bar, ep, lds_x, xrow_ld, 512);
    {
      float acc = 0.f;
#pragma unroll
      for (int p = 0; p < 4; ++p)
        acc += dot4(wa[p], *(const float4*)(lds_x + p * 256 + lane * 4));
#pragma unroll
      for (int p = 0; p < 4; ++p)
        acc += dot4(wa[4 + p], *(const float4*)(lds_h0 + p * 256 + lane * 4));
      acc = wred(acc);
      if (lane == 0) stcf(ws + E_OFF + gw, __expf(acc + ab));
    }
    ++ep; bar_arrive(bar, ep);
    if (MODE == 1 && bid == NBLK - 1 && t > 0)
      classifier8(lds_x, lin1_w, lin1_b, lin2_w, lin2_b,
                  out + (size_t)(t - 1) * 2, lds_big);

    // ---- B: wait e; inp[jB] = relu(Wx.x + (M.e)/sum(e) + b) — full row/wave ----
    bar_wait_stage(bar, ep, lds_e, ws + E_OFF, 1024);
    {
      float ax = 0.f, am = 0.f, es = 0.f;
#pragma unroll
      for (int p = 0; p < 4; ++p)
        ax += dot4(wxp[p], *(const float4*)(lds_x + p * 256 + lane * 4));
#pragma unroll
      for (int p = 0; p < 8; ++p) {
        float4 e4 = *(const float4*)(lds_e + p * 256 + lane * 4);
        am += dot4(wmp[p], e4);
        es += e4.x + e4.y + e4.z + e4.w;
      }
      ax = wred(ax); am = wred(am); es = wred(es);
      if ((wid & 1) == 0 && lane == 0)
        stcf(ws + INP_OFF + jB, fmaxf(ax + am / es + scb[wid >> 1], 0.f));
    }
    ++ep; bar_arrive(bar, ep);

    // ---- C: wait inp; LSTM layer 0 (h_prev = lds_h0) ----
    bar_wait_stage(bar, ep, lds_v, ws + INP_OFF, 512);
    {
      float a0 = 0.f, a1 = 0.f;
#pragma unroll
      for (int p = 0; p < 4; ++p) {
        float4 v4 = *(const float4*)(lds_v + p * 256 + lane * 4);
        float4 h4 = *(const float4*)(lds_h0 + p * 256 + lane * 4);
        a0 += dot4(wi0A[p], v4) + dot4(wh0A[p], h4);
        a1 += dot4(wi0B[p], v4) + dot4(wh0B[p], h4);
      }
      a0 = wred(a0); a1 = wred(a1);
      if (lane == 0) { sg[(wid >> 1) * 4 + gb] = a0; sg[(wid >> 1) * 4 + gb + 1] = a1; }
    }
    __syncthreads();
    if (tid < 4) {
      float gi = sg[tid * 4 + 0] + bs0[tid * 4 + 0];
      float gf = sg[tid * 4 + 1] + bs0[tid * 4 + 1];
      float gg = sg[tid * 4 + 2] + bs0[tid * 4 + 2];
      float go = sg[tid * 4 + 3] + bs0[tid * 4 + 3];
      float c = sigm(gf) * sc0[tid] + sigm(gi) * tanhf(gg);
      sc0[tid] = c;
      stcf(ws + H0_OFF + bid * 4 + tid, sigm(go) * tanhf(c));
    }
    ++ep; bar_arrive(bar, ep);

    // ---- D: wait h0'; LSTM layer 1 (h_prev = lds_x == h1(t-1)) ----
    bar_wait_stage(bar, ep, lds_h0, ws + H0_OFF, 512);
    if (t == 0) {   // h1(-1) = hidden[1], not x(0)=0
      *(float2*)(lds_x + tid * 2) = *(const float2*)(hidden + HD + tid * 2);
      __syncthreads();
    }
    {
      float a0 = 0.f, a1 = 0.f;
#pragma unroll
      for (int p = 0; p < 4; ++p) {
        float4 v4 = *(const float4*)(lds_h0 + p * 256 + lane * 4);
        float4 h4 = *(const float4*)(lds_x + p * 256 + lane * 4);
        a0 += dot4(wi1A[p], v4) + dot4(wh1A[p], h4);
        a1 += dot4(wi1B[p], v4) + dot4(wh1B[p], h4);
      }
      a0 = wred(a0); a1 = wred(a1);
      if (lane == 0) { sg[(wid >> 1) * 4 + gb] = a0; sg[(wid >> 1) * 4 + gb + 1] = a1; }
    }
    __syncthreads();
    if (tid < 4) {
      float gi = sg[tid * 4 + 0] + bs1[tid * 4 + 0];
      float gf = sg[tid * 4 + 1] + bs1[tid * 4 + 1];
      float gg = sg[tid * 4 + 2] + bs1[tid * 4 + 2];
      float go = sg[tid * 4 + 3] + bs1[tid * 4 + 3];
      float c = sigm(gf) * sc1_[tid] + sigm(gi) * tanhf(gg);
      sc1_[tid] = c;
      stcf(xrow_st + bid * 4 + tid, sigm(go) * tanhf(c));
    }
    ++ep; bar_arrive(bar, ep);
  }

  // ================= epilogue =================
  bar_wait_stage(bar, ep, nullptr, nullptr, 0);   // all final stores visible
  if (tid < 4) {
    out[4096 + 2 * HD + bid * 4 + tid] = sc0[tid];
    out[4096 + 3 * HD + bid * 4 + tid] = sc1_[tid];
  }
  if (bid == 0) {
    *(float2*)(out + 4096 + tid * 2) = *(const float2*)(lds_h0 + tid * 2);  // h0 final
    const float* xf = (MODE == 2) ? (ws + XH_OFF + (size_t)SD * HD) : (ws + X_OFF);
    float2 x2 = ldc2(xf + tid * 2);
    *(float2*)(out + 4096 + HD + tid * 2) = x2;                             // h1 final
  }
  if (MODE == 2) {
    // classifier for all steps: wave -> step tt = bid*8 + wid; outs[tt] = xh[tt+1]
    const int tt = bid * 8 + wid;
    const float* xr = ws + XH_OFF + (size_t)(tt + 1) * HD;
    float4 xv[4];
#pragma unroll
    for (int p = 0; p < 4; ++p) {
      float2 lo = ldc2(xr + p * 256 + lane * 4);
      float2 hi = ldc2(xr + p * 256 + lane * 4 + 2);
      xv[p].x = lo.x; xv[p].y = lo.y; xv[p].z = hi.x; xv[p].w = hi.y;
    }
    float* hid = lds_big + wid * 64;
#pragma unroll 2
    for (int o = 0; o < 64; ++o) {
      const float* wo = lin1_w + (size_t)o * HD;
      float acc = 0.f;
#pragma unroll
      for (int p = 0; p < 4; ++p)
        acc += dot4(*(const float4*)(wo + p * 256 + lane * 4), xv[p]);
      acc = wred(acc);
      if (lane == 0) hid[o] = fmaxf(acc + lin1_b[o], 0.f);
    }
    float hv = hid[lane];
    float r0 = wred(hv * lin2_w[lane]);
    float r1 = wred(hv * lin2_w[64 + lane]);
    if (lane == 0) {
      float l0 = r0 + lin2_b[0], l1 = r1 + lin2_b[1];
      float m = fmaxf(l0, l1);
      float e0 = __expf(l0 - m), e1 = __expf(l1 - m);
      float inv = 1.f / (e0 + e1);
      out[(size_t)tt * 2]     = e0 * inv;
      out[(size_t)tt * 2 + 1] = e1 * inv;
    }
  } else if (bid == NBLK - 1) {
    *(float2*)(lds_x + tid * 2) = ldc2(ws + X_OFF + tid * 2);
    __syncthreads();
    classifier8(lds_x, lin1_w, lin1_b, lin2_w, lin2_b,
                out + (size_t)(SD - 1) * 2, lds_big);
  }
}

extern "C" void kernel_launch(void* const* d_in, const int* in_sizes, int n_in,
                              void* d_out, int out_size, void* d_ws, size_t ws_size,
                              hipStream_t stream) {
  const float* enc    = (const float*)d_in[0];
  const float* hidden = (const float*)d_in[1];
  const float* cell   = (const float*)d_in[2];
  const float* attn_w = (const float*)d_in[3];
  const float* attn_b = (const float*)d_in[4];
  const float* comb_w = (const float*)d_in[5];
  const float* comb_b = (const float*)d_in[6];
  const float* w_ih   = (const float*)d_in[7];
  const float* w_hh   = (const float*)d_in[8];
  const float* b_ih   = (const float*)d_in[9];
  const float* b_hh   = (const float*)d_in[10];
  const float* lin1_w = (const float*)d_in[11];
  const float* lin1_b = (const float*)d_in[12];
  const float* lin2_w = (const float*)d_in[13];
  const float* lin2_b = (const float*)d_in[14];
  float* out = (float*)d_out;
  float* ws  = (float*)d_ws;

  hipMemsetAsync(d_ws, 0, 4096, stream);   // barrier flags
  if (ws_size >= WS_NEED_XH) {
    decoder_kernel<2><<<dim3(NBLK), dim3(TPB), 0, stream>>>(
        enc, attn_w, attn_b, comb_w, comb_b, w_ih, w_hh, b_ih, b_hh,
        lin1_w, lin1_b, lin2_w, lin2_b, hidden, cell, out, ws);
  } else {
    decoder_kernel<1><<<dim3(NBLK), dim3(TPB), 0, stream>>>(
        enc, attn_w, attn_b, comb_w, comb_b, w_ih, w_hh, b_ih, b_hh,
        lin1_w, lin1_b, lin2_w, lin2_b, hidden, cell, out, ws);
  }
  (void)in_sizes; (void)n_in; (void)out_size;
}

// Round 8
// 34067.661 us; speedup vs baseline: 1.8900x; 1.8900x over previous
//
#include <hip/hip_runtime.h>
#include <math.h>

#define SD   2048
#define HD   1024
#define TPB  512    // 8 waves
#define NBLK 256    // one block per CU

// ---- ws layout (float offsets); first 8KB = 8 replicated flag sets ----
#define E_OFF   2048
#define H0_OFF  4096
#define INP_OFF 5120
#define X_OFF   6144
#define M_OFF   8192                     // M[1024][2048] = comb_w[:,1024:] @ enc^T
#define M_SZ    (HD * SD)
#define XH_OFF  (M_OFF + M_SZ)           // xh[(SD+1)][HD] history (MODE2)
#define XH_SZ   ((SD + 1) * HD)
#define WS_NEED_M  ((size_t)(M_OFF + M_SZ + HD) * 4)
#define WS_NEED_XH ((size_t)(XH_OFF + XH_SZ) * 4)
#define FLAG_BYTES 8192

typedef unsigned long long u64;

// coherent accessors (sc1, bypass L1/L2; no cache-nuking fences)
__device__ __forceinline__ float ldcf(const float* p) {
  return __hip_atomic_load(p, __ATOMIC_RELAXED, __HIP_MEMORY_SCOPE_AGENT);
}
__device__ __forceinline__ float2 ldc2(const float* p) {
  u64 u = __hip_atomic_load((const u64*)p, __ATOMIC_RELAXED, __HIP_MEMORY_SCOPE_AGENT);
  union { u64 u; float2 f; } c; c.u = u; return c.f;
}
__device__ __forceinline__ void stcf(float* p, float v) {
  __hip_atomic_store(p, v, __ATOMIC_RELAXED, __HIP_MEMORY_SCOPE_AGENT);
}
__device__ __forceinline__ unsigned ldb(const unsigned* p) {
  return __hip_atomic_load(p, __ATOMIC_RELAXED, __HIP_MEMORY_SCOPE_AGENT);
}
__device__ __forceinline__ void stb(unsigned* p, unsigned v) {
  __hip_atomic_store(p, v, __ATOMIC_RELAXED, __HIP_MEMORY_SCOPE_AGENT);
}

__device__ __forceinline__ float dot4(float4 a, float4 b) {
  return a.x * b.x + a.y * b.y + a.z * b.z + a.w * b.w;
}
__device__ __forceinline__ float wred(float v) {
  v += __shfl_xor(v, 32, 64); v += __shfl_xor(v, 16, 64);
  v += __shfl_xor(v, 8, 64);  v += __shfl_xor(v, 4, 64);
  v += __shfl_xor(v, 2, 64);  v += __shfl_xor(v, 1, 64);
  return v;
}
__device__ __forceinline__ float sigm(float x) { return 1.0f / (1.0f + __expf(-x)); }

// ---- producer-broadcast barrier: each block, at arrive, writes its epoch
// into 8 replicated flag sets (one per 32-block consumer group). Consumer
// group g flat-polls ONLY set g -> <=32 readers per flag line (R5's proven
// readership), sleep-paced. Removes the master-detect and replica-store
// hops of R5: chain = arrive-stores || -> consumer detect -> stage.
__device__ __forceinline__ void bar_arrive(unsigned* bar, unsigned ep) {
  __syncthreads();                        // drains vmcnt -> sc1 data stores visible
  if (threadIdx.x < 8) stb(bar + threadIdx.x * 256 + blockIdx.x, ep);
}
__device__ __forceinline__ void bar_wait(unsigned* bar, unsigned ep) {
  const unsigned* fs = bar + ((blockIdx.x >> 5) * 256);
  if (threadIdx.x < 64) {
    const int lane = threadIdx.x;
    unsigned m;
    for (;;) {
      unsigned a = ldb(fs + lane),       b = ldb(fs + 64 + lane);
      unsigned c = ldb(fs + 128 + lane), d = ldb(fs + 192 + lane);
      unsigned ab = a < b ? a : b, cd = c < d ? c : d;
      m = ab < cd ? ab : cd;
#pragma unroll
      for (int s = 32; s; s >>= 1) {
        unsigned o = (unsigned)__shfl_xor((int)m, s, 64);
        m = m < o ? m : o;
      }
      if (m >= ep) break;
      __builtin_amdgcn_s_sleep(1);
    }
  }
  __syncthreads();
}

// 8-wave classifier (MODE1 in-loop / final)
__device__ void classifier8(const float* smx, const float* __restrict__ lin1_w,
                            const float* __restrict__ lin1_b,
                            const float* __restrict__ lin2_w,
                            const float* __restrict__ lin2_b,
                            float* __restrict__ out2, float* scratch) {
  const int tid = threadIdx.x, wid = tid >> 6, lane = tid & 63;
#pragma unroll
  for (int oi = 0; oi < 8; ++oi) {
    const int o = wid * 8 + oi;
    float acc = 0.f;
#pragma unroll
    for (int p = 0; p < 4; ++p)
      acc += dot4(*(const float4*)(lin1_w + (size_t)o * HD + p * 256 + lane * 4),
                  *(const float4*)(smx + p * 256 + lane * 4));
    acc = wred(acc);
    if (lane == 0) scratch[o] = fmaxf(acc + lin1_b[o], 0.f);
  }
  __syncthreads();
  if (tid < 64) {
    float hv = scratch[tid];
    float r0 = wred(hv * lin2_w[tid]);
    float r1 = wred(hv * lin2_w[64 + tid]);
    if (tid == 0) {
      float l0 = r0 + lin2_b[0], l1 = r1 + lin2_b[1];
      float m = fmaxf(l0, l1);
      float e0 = __expf(l0 - m), e1 = __expf(l1 - m);
      float inv = 1.f / (e0 + e1);
      out2[0] = e0 * inv; out2[1] = e1 * inv;
    }
  }
  __syncthreads();
}

template <int MODE>   // 2: xh history + epilogue classifier; 1: in-loop classifier
__global__ void __launch_bounds__(TPB, 2)
decoder_kernel(const float* __restrict__ enc, const float* __restrict__ attn_w,
               const float* __restrict__ attn_b, const float* __restrict__ comb_w,
               const float* __restrict__ comb_b, const float* __restrict__ w_ih,
               const float* __restrict__ w_hh, const float* __restrict__ b_ih,
               const float* __restrict__ b_hh, const float* __restrict__ lin1_w,
               const float* __restrict__ lin1_b, const float* __restrict__ lin2_w,
               const float* __restrict__ lin2_b, const float* __restrict__ hidden,
               const float* __restrict__ cell, float* __restrict__ out,
               float* __restrict__ ws) {
  __shared__ __align__(16) float lds_x[HD];
  __shared__ __align__(16) float lds_h0[HD];
  __shared__ __align__(16) float lds_e[SD];
  __shared__ __align__(16) float lds_v[HD];
  __shared__ __align__(16) float lds_big[8 * HD];
  __shared__ float sg[16], sb[24], bs0[16], bs1[16], scb[4], sc0[4], sc1_[4];

  const int tid = threadIdx.x, wid = tid >> 6, lane = tid & 63;
  const int bid = blockIdx.x;
  unsigned* bar = (unsigned*)ws;
  unsigned ep = 0;

  // ================= prologue: M = comb_w[:,1024:] @ enc^T =================
  {
    const int j0 = (bid >> 3) * 32, i0 = (bid & 7) * 256;
    float4 cw0[4], cw1[4], cw2[4], cw3[4];
#pragma unroll
    for (int p = 0; p < 4; ++p) {
      cw0[p] = *(const float4*)(comb_w + (size_t)(j0 + wid * 4 + 0) * 2048 + 1024 + p * 256 + lane * 4);
      cw1[p] = *(const float4*)(comb_w + (size_t)(j0 + wid * 4 + 1) * 2048 + 1024 + p * 256 + lane * 4);
      cw2[p] = *(const float4*)(comb_w + (size_t)(j0 + wid * 4 + 2) * 2048 + 1024 + p * 256 + lane * 4);
      cw3[p] = *(const float4*)(comb_w + (size_t)(j0 + wid * 4 + 3) * 2048 + 1024 + p * 256 + lane * 4);
    }
    for (int ib = 0; ib < 32; ++ib) {
      const int rl = tid >> 6, cs = (tid & 63) * 16;
      const float* src = enc + (size_t)(i0 + ib * 8 + rl) * HD + cs;
#pragma unroll
      for (int q = 0; q < 4; ++q)
        *(float4*)(lds_big + rl * HD + cs + q * 4) = *(const float4*)(src + q * 4);
      __syncthreads();
#pragma unroll 1
      for (int ii = 0; ii < 8; ++ii) {
        float a0 = 0.f, a1 = 0.f, a2 = 0.f, a3 = 0.f;
#pragma unroll
        for (int p = 0; p < 4; ++p) {
          float4 e4 = *(const float4*)(lds_big + ii * HD + p * 256 + lane * 4);
          a0 += dot4(cw0[p], e4); a1 += dot4(cw1[p], e4);
          a2 += dot4(cw2[p], e4); a3 += dot4(cw3[p], e4);
        }
        a0 = wred(a0); a1 = wred(a1); a2 = wred(a2); a3 = wred(a3);
        if (lane == 0) {
          const int i = i0 + ib * 8 + ii;
          stcf(ws + M_OFF + (size_t)(j0 + wid * 4 + 0) * SD + i, a0);
          stcf(ws + M_OFF + (size_t)(j0 + wid * 4 + 1) * SD + i, a1);
          stcf(ws + M_OFF + (size_t)(j0 + wid * 4 + 2) * SD + i, a2);
          stcf(ws + M_OFF + (size_t)(j0 + wid * 4 + 3) * SD + i, a3);
        }
      }
      __syncthreads();
    }
  }
  // recurrent-state init
  float* xrow0 = (MODE == 2) ? (ws + XH_OFF) : (ws + X_OFF);
  if (bid == 0) { stcf(xrow0 + tid, 0.f); stcf(xrow0 + 512 + tid, 0.f); }
  *(float2*)(lds_h0 + tid * 2) = *(const float2*)(hidden + tid * 2);
  if (tid < 16) {
    const int g = tid & 3, k = bid * 4 + (tid >> 2);
    bs0[tid] = b_ih[g * HD + k] + b_hh[g * HD + k];
    bs1[tid] = b_ih[4 * HD + g * HD + k] + b_hh[4 * HD + g * HD + k];
  }
  if (tid < 4) {
    scb[tid]  = comb_b[bid * 4 + tid];
    sc0[tid]  = cell[bid * 4 + tid];
    sc1_[tid] = cell[HD + bid * 4 + tid];
  }
  ++ep; bar_arrive(bar, ep); bar_wait(bar, ep);   // M + x(0) visible

  // ================= pin per-wave weight rows =================
  const int gw = bid * 8 + wid;                 // attn row
  float4 wa[8]; float ab = attn_b[gw];
#pragma unroll
  for (int p = 0; p < 8; ++p)
    wa[p] = *(const float4*)(attn_w + (size_t)gw * 2048 + p * 256 + lane * 4);
  const int jB = bid * 4 + (wid >> 1), half = wid & 1;   // comb/M row (2 waves/row)
  float4 wxp[2], wmp[4];
#pragma unroll
  for (int p = 0; p < 2; ++p)
    wxp[p] = *(const float4*)(comb_w + (size_t)jB * 2048 + half * 512 + p * 256 + lane * 4);
#pragma unroll
  for (int p = 0; p < 4; ++p)
    wmp[p] = *(const float4*)(ws + M_OFF + (size_t)jB * SD + half * 1024 + p * 256 + lane * 4);
  const int kC = bid * 4 + (wid >> 1), gb = (wid & 1) * 2;
  float4 wi0A[4], wi0B[4], wh0A[4], wh0B[4], wi1A[4], wi1B[4], wh1A[4], wh1B[4];
#pragma unroll
  for (int p = 0; p < 4; ++p) {
    wi0A[p] = *(const float4*)(w_ih + (size_t)((gb + 0) * HD + kC) * HD + p * 256 + lane * 4);
    wi0B[p] = *(const float4*)(w_ih + (size_t)((gb + 1) * HD + kC) * HD + p * 256 + lane * 4);
    wh0A[p] = *(const float4*)(w_hh + (size_t)((gb + 0) * HD + kC) * HD + p * 256 + lane * 4);
    wh0B[p] = *(const float4*)(w_hh + (size_t)((gb + 1) * HD + kC) * HD + p * 256 + lane * 4);
    wi1A[p] = *(const float4*)(w_ih + (size_t)4 * HD * HD + (size_t)((gb + 0) * HD + kC) * HD + p * 256 + lane * 4);
    wi1B[p] = *(const float4*)(w_ih + (size_t)4 * HD * HD + (size_t)((gb + 1) * HD + kC) * HD + p * 256 + lane * 4);
    wh1A[p] = *(const float4*)(w_hh + (size_t)4 * HD * HD + (size_t)((gb + 0) * HD + kC) * HD + p * 256 + lane * 4);
    wh1B[p] = *(const float4*)(w_hh + (size_t)4 * HD * HD + (size_t)((gb + 1) * HD + kC) * HD + p * 256 + lane * 4);
  }

  // ================= main loop: 4 flag-phases/step =================
  for (int t = 0; t < SD; ++t) {
    const float* xrow_ld = (MODE == 2) ? (ws + XH_OFF + (size_t)t * HD) : (ws + X_OFF);
    float* xrow_st = (MODE == 2) ? (ws + XH_OFF + (size_t)(t + 1) * HD) : (ws + X_OFF);

    // ---- A: stage x(t); e[gw] = exp(attn_row . [x;h0] + b) ----
    *(float2*)(lds_x + tid * 2) = ldc2(xrow_ld + tid * 2);
    __syncthreads();
    {
      float acc = 0.f;
#pragma unroll
      for (int p = 0; p < 4; ++p)
        acc += dot4(wa[p], *(const float4*)(lds_x + p * 256 + lane * 4));
#pragma unroll
      for (int p = 0; p < 4; ++p)
        acc += dot4(wa[4 + p], *(const float4*)(lds_h0 + p * 256 + lane * 4));
      acc = wred(acc);
      if (lane == 0) stcf(ws + E_OFF + gw, __expf(acc + ab));
    }
    ++ep; bar_arrive(bar, ep);
    if (MODE == 1 && bid == NBLK - 1 && t > 0)
      classifier8(lds_x, lin1_w, lin1_b, lin2_w, lin2_b,
                  out + (size_t)(t - 1) * 2, lds_big);
    bar_wait(bar, ep);

    // ---- B: stage e; inp[j] = relu(Wx.x + (M.e)/sum(e) + b) ----
    *(float2*)(lds_e + tid * 2)        = ldc2(ws + E_OFF + tid * 2);
    *(float2*)(lds_e + 1024 + tid * 2) = ldc2(ws + E_OFF + 1024 + tid * 2);
    __syncthreads();
    {
      float axh = 0.f, amh = 0.f, esh = 0.f;
#pragma unroll
      for (int p = 0; p < 2; ++p)
        axh += dot4(wxp[p], *(const float4*)(lds_x + half * 512 + p * 256 + lane * 4));
#pragma unroll
      for (int p = 0; p < 4; ++p) {
        float4 e4 = *(const float4*)(lds_e + half * 1024 + p * 256 + lane * 4);
        amh += dot4(wmp[p], e4);
        esh += e4.x + e4.y + e4.z + e4.w;
      }
      axh = wred(axh); amh = wred(amh); esh = wred(esh);
      if (lane == 0) { sb[wid * 3] = axh; sb[wid * 3 + 1] = amh; sb[wid * 3 + 2] = esh; }
    }
    __syncthreads();
    if (tid < 4) {
      float ax = sb[tid * 6] + sb[tid * 6 + 3];
      float am = sb[tid * 6 + 1] + sb[tid * 6 + 4];
      float es = sb[tid * 6 + 2] + sb[tid * 6 + 5];
      stcf(ws + INP_OFF + bid * 4 + tid, fmaxf(ax + am / es + scb[tid], 0.f));
    }
    ++ep; bar_arrive(bar, ep); bar_wait(bar, ep);

    // ---- C: stage inp; LSTM layer 0 (h_prev = lds_h0) ----
    *(float2*)(lds_v + tid * 2) = ldc2(ws + INP_OFF + tid * 2);
    __syncthreads();
    {
      float a0 = 0.f, a1 = 0.f;
#pragma unroll
      for (int p = 0; p < 4; ++p) {
        float4 v4 = *(const float4*)(lds_v + p * 256 + lane * 4);
        float4 h4 = *(const float4*)(lds_h0 + p * 256 + lane * 4);
        a0 += dot4(wi0A[p], v4) + dot4(wh0A[p], h4);
        a1 += dot4(wi0B[p], v4) + dot4(wh0B[p], h4);
      }
      a0 = wred(a0); a1 = wred(a1);
      if (lane == 0) { sg[(wid >> 1) * 4 + gb] = a0; sg[(wid >> 1) * 4 + gb + 1] = a1; }
    }
    __syncthreads();
    if (tid < 4) {
      float gi = sg[tid * 4 + 0] + bs0[tid * 4 + 0];
      float gf = sg[tid * 4 + 1] + bs0[tid * 4 + 1];
      float gg = sg[tid * 4 + 2] + bs0[tid * 4 + 2];
      float go = sg[tid * 4 + 3] + bs0[tid * 4 + 3];
      float c = sigm(gf) * sc0[tid] + sigm(gi) * tanhf(gg);
      sc0[tid] = c;
      stcf(ws + H0_OFF + bid * 4 + tid, sigm(go) * tanhf(c));
    }
    ++ep; bar_arrive(bar, ep); bar_wait(bar, ep);

    // ---- D: stage h0'; LSTM layer 1 (h_prev = lds_x == h1(t-1)) ----
    *(float2*)(lds_h0 + tid * 2) = ldc2(ws + H0_OFF + tid * 2);
    if (t == 0)   // h1(-1) = hidden[1], not x(0)=0
      *(float2*)(lds_x + tid * 2) = *(const float2*)(hidden + HD + tid * 2);
    __syncthreads();
    {
      float a0 = 0.f, a1 = 0.f;
#pragma unroll
      for (int p = 0; p < 4; ++p) {
        float4 v4 = *(const float4*)(lds_h0 + p * 256 + lane * 4);
        float4 h4 = *(const float4*)(lds_x + p * 256 + lane * 4);
        a0 += dot4(wi1A[p], v4) + dot4(wh1A[p], h4);
        a1 += dot4(wi1B[p], v4) + dot4(wh1B[p], h4);
      }
      a0 = wred(a0); a1 = wred(a1);
      if (lane == 0) { sg[(wid >> 1) * 4 + gb] = a0; sg[(wid >> 1) * 4 + gb + 1] = a1; }
    }
    __syncthreads();
    if (tid < 4) {
      float gi = sg[tid * 4 + 0] + bs1[tid * 4 + 0];
      float gf = sg[tid * 4 + 1] + bs1[tid * 4 + 1];
      float gg = sg[tid * 4 + 2] + bs1[tid * 4 + 2];
      float go = sg[tid * 4 + 3] + bs1[tid * 4 + 3];
      float c = sigm(gf) * sc1_[tid] + sigm(gi) * tanhf(gg);
      sc1_[tid] = c;
      stcf(xrow_st + bid * 4 + tid, sigm(go) * tanhf(c));
    }
    ++ep; bar_arrive(bar, ep); bar_wait(bar, ep);
  }

  // ================= epilogue =================
  if (tid < 4) {
    out[4096 + 2 * HD + bid * 4 + tid] = sc0[tid];
    out[4096 + 3 * HD + bid * 4 + tid] = sc1_[tid];
  }
  if (bid == 0) {
    *(float2*)(out + 4096 + tid * 2) = *(const float2*)(lds_h0 + tid * 2);  // h0 final
    const float* xf = (MODE == 2) ? (ws + XH_OFF + (size_t)SD * HD) : (ws + X_OFF);
    float2 x2 = ldc2(xf + tid * 2);
    *(float2*)(out + 4096 + HD + tid * 2) = x2;                             // h1 final
  }
  if (MODE == 2) {
    // classifier for all steps: wave -> step tt = bid*8 + wid; outs[tt] = xh[tt+1]
    const int tt = bid * 8 + wid;
    const float* xr = ws + XH_OFF + (size_t)(tt + 1) * HD;
    float4 xv[4];
#pragma unroll
    for (int p = 0; p < 4; ++p) {
      float2 lo = ldc2(xr + p * 256 + lane * 4);
      float2 hi = ldc2(xr + p * 256 + lane * 4 + 2);
      xv[p].x = lo.x; xv[p].y = lo.y; xv[p].z = hi.x; xv[p].w = hi.y;
    }
    float* hid = lds_big + wid * 64;
#pragma unroll 2
    for (int o = 0; o < 64; ++o) {
      const float* wo = lin1_w + (size_t)o * HD;
      float acc = 0.f;
#pragma unroll
      for (int p = 0; p < 4; ++p)
        acc += dot4(*(const float4*)(wo + p * 256 + lane * 4), xv[p]);
      acc = wred(acc);
      if (lane == 0) hid[o] = fmaxf(acc + lin1_b[o], 0.f);
    }
    float hv = hid[lane];
    float r0 = wred(hv * lin2_w[lane]);
    float r1 = wred(hv * lin2_w[64 + lane]);
    if (lane == 0) {
      float l0 = r0 + lin2_b[0], l1 = r1 + lin2_b[1];
      float m = fmaxf(l0, l1);
      float e0 = __expf(l0 - m), e1 = __expf(l1 - m);
      float inv = 1.f / (e0 + e1);
      out[(size_t)tt * 2]     = e0 * inv;
      out[(size_t)tt * 2 + 1] = e1 * inv;
    }
  } else if (bid == NBLK - 1) {
    *(float2*)(lds_x + tid * 2) = ldc2(ws + X_OFF + tid * 2);
    __syncthreads();
    classifier8(lds_x, lin1_w, lin1_b, lin2_w, lin2_b,
                out + (size_t)(SD - 1) * 2, lds_big);
  }
}

extern "C" void kernel_launch(void* const* d_in, const int* in_sizes, int n_in,
                              void* d_out, int out_size, void* d_ws, size_t ws_size,
                              hipStream_t stream) {
  const float* enc    = (const float*)d_in[0];
  const float* hidden = (const float*)d_in[1];
  const float* cell   = (const float*)d_in[2];
  const float* attn_w = (const float*)d_in[3];
  const float* attn_b = (const float*)d_in[4];
  const float* comb_w = (const float*)d_in[5];
  const float* comb_b = (const float*)d_in[6];
  const float* w_ih   = (const float*)d_in[7];
  const float* w_hh   = (const float*)d_in[8];
  const float* b_ih   = (const float*)d_in[9];
  const float* b_hh   = (const float*)d_in[10];
  const float* lin1_w = (const float*)d_in[11];
  const float* lin1_b = (const float*)d_in[12];
  const float* lin2_w = (const float*)d_in[13];
  const float* lin2_b = (const float*)d_in[14];
  float* out = (float*)d_out;
  float* ws  = (float*)d_ws;

  hipMemsetAsync(d_ws, 0, FLAG_BYTES, stream);   // 8 replicated flag sets
  if (ws_size >= WS_NEED_XH) {
    decoder_kernel<2><<<dim3(NBLK), dim3(TPB), 0, stream>>>(
        enc, attn_w, attn_b, comb_w, comb_b, w_ih, w_hh, b_ih, b_hh,
        lin1_w, lin1_b, lin2_w, lin2_b, hidden, cell, out, ws);
  } else {
    decoder_kernel<1><<<dim3(NBLK), dim3(TPB), 0, stream>>>(
        enc, attn_w, attn_b, comb_w, comb_b, w_ih, w_hh, b_ih, b_hh,
        lin1_w, lin1_b, lin2_w, lin2_b, hidden, cell, out, ws);
  }
  (void)in_sizes; (void)n_in; (void)out_size;
}

// Round 9
// 26660.547 us; speedup vs baseline: 2.4151x; 1.2778x over previous
//
#include <hip/hip_runtime.h>
#include <math.h>

#define SD   2048
#define HD   1024
#define TPB  512    // 8 waves
#define NBLK 256    // one block per CU

// ---- ws layout (bytes); first 4KB = flag barrier (prologue/epilogue only) ----
#define E2_BYTE   4096                        // u64[2][2048] tagged e
#define I2_BYTE   (E2_BYTE + 2 * 2048 * 8)    // u64[2][1024] tagged inp
#define H2_BYTE   (I2_BYTE + 2 * 1024 * 8)    // u64[2][1024] tagged h0
#define X2_BYTE   (H2_BYTE + 2 * 1024 * 8)    // u64[2][1024] tagged x
#define TAG_END   (X2_BYTE + 2 * 1024 * 8)    // 86016
#define M_BYTE    131072                      // float[1024][2048]
#define XH_BYTE   (M_BYTE + (size_t)HD * SD * 4)
#define WS_NEED_XH (XH_BYTE + (size_t)(SD + 1) * HD * 4)

typedef unsigned long long u64;

// coherent accessors (sc1, bypass L1/L2; no cache-nuking fences)
__device__ __forceinline__ float ldcf(const float* p) {
  return __hip_atomic_load(p, __ATOMIC_RELAXED, __HIP_MEMORY_SCOPE_AGENT);
}
__device__ __forceinline__ float2 ldc2(const float* p) {
  u64 u = __hip_atomic_load((const u64*)p, __ATOMIC_RELAXED, __HIP_MEMORY_SCOPE_AGENT);
  union { u64 u; float2 f; } c; c.u = u; return c.f;
}
__device__ __forceinline__ void stcf(float* p, float v) {
  __hip_atomic_store(p, v, __ATOMIC_RELAXED, __HIP_MEMORY_SCOPE_AGENT);
}
__device__ __forceinline__ u64 ldc8(const u64* p) {
  return __hip_atomic_load(p, __ATOMIC_RELAXED, __HIP_MEMORY_SCOPE_AGENT);
}
__device__ __forceinline__ void stc8(u64* p, u64 v) {
  __hip_atomic_store(p, v, __ATOMIC_RELAXED, __HIP_MEMORY_SCOPE_AGENT);
}
__device__ __forceinline__ unsigned ldb(const unsigned* p) {
  return __hip_atomic_load(p, __ATOMIC_RELAXED, __HIP_MEMORY_SCOPE_AGENT);
}
__device__ __forceinline__ void stb(unsigned* p, unsigned v) {
  __hip_atomic_store(p, v, __ATOMIC_RELAXED, __HIP_MEMORY_SCOPE_AGENT);
}

__device__ __forceinline__ u64 pk(float v, unsigned tag) {
  union { float f; unsigned u; } c; c.f = v;
  return ((u64)tag << 32) | (u64)c.u;
}
__device__ __forceinline__ float pv(u64 u) {
  union { unsigned u; float f; } c; c.u = (unsigned)u; return c.f;
}

__device__ __forceinline__ float dot4(float4 a, float4 b) {
  return a.x * b.x + a.y * b.y + a.z * b.z + a.w * b.w;
}
__device__ __forceinline__ float wred(float v) {
  v += __shfl_xor(v, 32, 64); v += __shfl_xor(v, 16, 64);
  v += __shfl_xor(v, 8, 64);  v += __shfl_xor(v, 4, 64);
  v += __shfl_xor(v, 2, 64);  v += __shfl_xor(v, 1, 64);
  return v;
}
__device__ __forceinline__ float sigm(float x) { return 1.0f / (1.0f + __expf(-x)); }

// tagged stage: one wave stages 512 contiguous u64 entries (8/lane) into LDS.
// Batched issue (one LLC RT per round), s_sleep pacing, static-indexed v[8].
__device__ __forceinline__ void stage8(const u64* __restrict__ src,
                                       float* __restrict__ dst,
                                       unsigned T, int lane) {
  u64 v[8];
  unsigned done = 0;
  for (;;) {
#pragma unroll
    for (int s = 0; s < 8; ++s)
      if (!(done & (1u << s))) v[s] = ldc8(src + s * 64 + lane);
#pragma unroll
    for (int s = 0; s < 8; ++s)
      if (!(done & (1u << s)) && (unsigned)(v[s] >> 32) >= T) {
        dst[s * 64 + lane] = pv(v[s]);
        done |= (1u << s);
      }
    if (__all((int)(done == 255u))) break;
    __builtin_amdgcn_s_sleep(1);
  }
}

// ---- R5 two-hop flag barrier (prologue/epilogue only) ----
__device__ __forceinline__ void bar_arrive(unsigned* bar, unsigned ep) {
  __syncthreads();
  if (threadIdx.x == 0) stb(bar + blockIdx.x, ep);
}
__device__ __forceinline__ void bar_wait(unsigned* bar, unsigned ep) {
  if (blockIdx.x == 0) {
    if (threadIdx.x < 64) {
      const int lane = threadIdx.x;
      unsigned m;
      do {
        unsigned a = ldb(bar + lane),       b = ldb(bar + 64 + lane);
        unsigned c = ldb(bar + 128 + lane), d = ldb(bar + 192 + lane);
        unsigned ab = a < b ? a : b, cd = c < d ? c : d;
        m = ab < cd ? ab : cd;
#pragma unroll
        for (int s = 32; s; s >>= 1) {
          unsigned o = (unsigned)__shfl_xor((int)m, s, 64);
          m = m < o ? m : o;
        }
      } while (m < ep);
      if (lane < 8) stb(bar + 256 + lane * 16, ep);
    }
  } else if (threadIdx.x == 0) {
    while (ldb(bar + 256 + (blockIdx.x & 7) * 16) < ep)
      __builtin_amdgcn_s_sleep(1);
  }
  __syncthreads();
}

// 8-wave classifier (MODE1 in-loop / final)
__device__ void classifier8(const float* smx, const float* __restrict__ lin1_w,
                            const float* __restrict__ lin1_b,
                            const float* __restrict__ lin2_w,
                            const float* __restrict__ lin2_b,
                            float* __restrict__ out2, float* scratch) {
  const int tid = threadIdx.x, wid = tid >> 6, lane = tid & 63;
#pragma unroll
  for (int oi = 0; oi < 8; ++oi) {
    const int o = wid * 8 + oi;
    float acc = 0.f;
#pragma unroll
    for (int p = 0; p < 4; ++p)
      acc += dot4(*(const float4*)(lin1_w + (size_t)o * HD + p * 256 + lane * 4),
                  *(const float4*)(smx + p * 256 + lane * 4));
    acc = wred(acc);
    if (lane == 0) scratch[o] = fmaxf(acc + lin1_b[o], 0.f);
  }
  __syncthreads();
  if (tid < 64) {
    float hv = scratch[tid];
    float r0 = wred(hv * lin2_w[tid]);
    float r1 = wred(hv * lin2_w[64 + tid]);
    if (tid == 0) {
      float l0 = r0 + lin2_b[0], l1 = r1 + lin2_b[1];
      float m = fmaxf(l0, l1);
      float e0 = __expf(l0 - m), e1 = __expf(l1 - m);
      float inv = 1.f / (e0 + e1);
      out2[0] = e0 * inv; out2[1] = e1 * inv;
    }
  }
  __syncthreads();
}

template <int MODE>   // 2: xh history + epilogue classifier; 1: in-loop classifier
__global__ void __launch_bounds__(TPB, 2)
decoder_kernel(const float* __restrict__ enc, const float* __restrict__ attn_w,
               const float* __restrict__ attn_b, const float* __restrict__ comb_w,
               const float* __restrict__ comb_b, const float* __restrict__ w_ih,
               const float* __restrict__ w_hh, const float* __restrict__ b_ih,
               const float* __restrict__ b_hh, const float* __restrict__ lin1_w,
               const float* __restrict__ lin1_b, const float* __restrict__ lin2_w,
               const float* __restrict__ lin2_b, const float* __restrict__ hidden,
               const float* __restrict__ cell, float* __restrict__ out,
               float* __restrict__ ws) {
  __shared__ __align__(16) float lds_x[HD];
  __shared__ __align__(16) float lds_h0[HD];
  __shared__ __align__(16) float lds_e[SD];
  __shared__ __align__(16) float lds_v[HD];
  __shared__ __align__(16) float lds_big[8 * HD];
  __shared__ float sg[16], sb[24], bs0[16], bs1[16], scb[4], sc0[4], sc1_[4];

  const int tid = threadIdx.x, wid = tid >> 6, lane = tid & 63;
  const int bid = blockIdx.x;
  unsigned* bar = (unsigned*)ws;
  u64* E2 = (u64*)((char*)ws + E2_BYTE);
  u64* I2 = (u64*)((char*)ws + I2_BYTE);
  u64* H2 = (u64*)((char*)ws + H2_BYTE);
  u64* X2 = (u64*)((char*)ws + X2_BYTE);
  float* M  = (float*)((char*)ws + M_BYTE);
  float* xh = (float*)((char*)ws + XH_BYTE);

  // ================= prologue: M = comb_w[:,1024:] @ enc^T =================
  {
    const int j0 = (bid >> 3) * 32, i0 = (bid & 7) * 256;
    float4 cw0[4], cw1[4], cw2[4], cw3[4];
#pragma unroll
    for (int p = 0; p < 4; ++p) {
      cw0[p] = *(const float4*)(comb_w + (size_t)(j0 + wid * 4 + 0) * 2048 + 1024 + p * 256 + lane * 4);
      cw1[p] = *(const float4*)(comb_w + (size_t)(j0 + wid * 4 + 1) * 2048 + 1024 + p * 256 + lane * 4);
      cw2[p] = *(const float4*)(comb_w + (size_t)(j0 + wid * 4 + 2) * 2048 + 1024 + p * 256 + lane * 4);
      cw3[p] = *(const float4*)(comb_w + (size_t)(j0 + wid * 4 + 3) * 2048 + 1024 + p * 256 + lane * 4);
    }
    for (int ib = 0; ib < 32; ++ib) {
      const int rl = tid >> 6, cs = (tid & 63) * 16;
      const float* src = enc + (size_t)(i0 + ib * 8 + rl) * HD + cs;
#pragma unroll
      for (int q = 0; q < 4; ++q)
        *(float4*)(lds_big + rl * HD + cs + q * 4) = *(const float4*)(src + q * 4);
      __syncthreads();
#pragma unroll 1
      for (int ii = 0; ii < 8; ++ii) {
        float a0 = 0.f, a1 = 0.f, a2 = 0.f, a3 = 0.f;
#pragma unroll
        for (int p = 0; p < 4; ++p) {
          float4 e4 = *(const float4*)(lds_big + ii * HD + p * 256 + lane * 4);
          a0 += dot4(cw0[p], e4); a1 += dot4(cw1[p], e4);
          a2 += dot4(cw2[p], e4); a3 += dot4(cw3[p], e4);
        }
        a0 = wred(a0); a1 = wred(a1); a2 = wred(a2); a3 = wred(a3);
        if (lane == 0) {
          const int i = i0 + ib * 8 + ii;
          stcf(M + (size_t)(j0 + wid * 4 + 0) * SD + i, a0);
          stcf(M + (size_t)(j0 + wid * 4 + 1) * SD + i, a1);
          stcf(M + (size_t)(j0 + wid * 4 + 2) * SD + i, a2);
          stcf(M + (size_t)(j0 + wid * 4 + 3) * SD + i, a3);
        }
      }
      __syncthreads();
    }
  }
  // recurrent-state init (x(0)=0 comes from the zeroed X2 parity-0 tags)
  *(float2*)(lds_h0 + tid * 2) = *(const float2*)(hidden + tid * 2);
  if (tid < 16) {
    const int g = tid & 3, k = bid * 4 + (tid >> 2);
    bs0[tid] = b_ih[g * HD + k] + b_hh[g * HD + k];
    bs1[tid] = b_ih[4 * HD + g * HD + k] + b_hh[4 * HD + g * HD + k];
  }
  if (tid < 4) {
    scb[tid]  = comb_b[bid * 4 + tid];
    sc0[tid]  = cell[bid * 4 + tid];
    sc1_[tid] = cell[HD + bid * 4 + tid];
  }
  bar_arrive(bar, 1); bar_wait(bar, 1);   // M visible before pinning

  // ================= pin per-wave weight rows =================
  const int gw = bid * 8 + wid;                 // attn row
  float4 wa[8]; float ab = attn_b[gw];
#pragma unroll
  for (int p = 0; p < 8; ++p)
    wa[p] = *(const float4*)(attn_w + (size_t)gw * 2048 + p * 256 + lane * 4);
  const int jB = bid * 4 + (wid >> 1), half = wid & 1;   // comb/M row (2 waves/row)
  float4 wxp[2], wmp[4];
#pragma unroll
  for (int p = 0; p < 2; ++p)
    wxp[p] = *(const float4*)(comb_w + (size_t)jB * 2048 + half * 512 + p * 256 + lane * 4);
#pragma unroll
  for (int p = 0; p < 4; ++p)
    wmp[p] = *(const float4*)(M + (size_t)jB * SD + half * 1024 + p * 256 + lane * 4);
  const int kC = bid * 4 + (wid >> 1), gb = (wid & 1) * 2;
  float4 wi0A[4], wi0B[4], wh0A[4], wh0B[4], wi1A[4], wi1B[4], wh1A[4], wh1B[4];
#pragma unroll
  for (int p = 0; p < 4; ++p) {
    wi0A[p] = *(const float4*)(w_ih + (size_t)((gb + 0) * HD + kC) * HD + p * 256 + lane * 4);
    wi0B[p] = *(const float4*)(w_ih + (size_t)((gb + 1) * HD + kC) * HD + p * 256 + lane * 4);
    wh0A[p] = *(const float4*)(w_hh + (size_t)((gb + 0) * HD + kC) * HD + p * 256 + lane * 4);
    wh0B[p] = *(const float4*)(w_hh + (size_t)((gb + 1) * HD + kC) * HD + p * 256 + lane * 4);
    wi1A[p] = *(const float4*)(w_ih + (size_t)4 * HD * HD + (size_t)((gb + 0) * HD + kC) * HD + p * 256 + lane * 4);
    wi1B[p] = *(const float4*)(w_ih + (size_t)4 * HD * HD + (size_t)((gb + 1) * HD + kC) * HD + p * 256 + lane * 4);
    wh1A[p] = *(const float4*)(w_hh + (size_t)4 * HD * HD + (size_t)((gb + 0) * HD + kC) * HD + p * 256 + lane * 4);
    wh1B[p] = *(const float4*)(w_hh + (size_t)4 * HD * HD + (size_t)((gb + 1) * HD + kC) * HD + p * 256 + lane * 4);
  }

  // ================= main loop: tagged dataflow, paced wave-polls =================
  for (int t = 0; t < SD; ++t) {
    const int par = t & 1;
    const unsigned tb = (unsigned)(t * 4);
    u64* E2p = E2 + (size_t)par * 2048;
    u64* I2p = I2 + (size_t)par * 1024;
    u64* H2p = H2 + (size_t)par * 1024;
    u64* X2p = X2 + (size_t)par * 1024;
    u64* X2n = X2 + (size_t)((t + 1) & 1) * 1024;

    // ---- A: stage x(t) [waves 0-1]; e[gw] = exp(attn_row.[x;h0]+b) ----
    if (wid < 2) stage8(X2p + wid * 512, lds_x + wid * 512, tb, lane);
    __syncthreads();
    {
      float acc = 0.f;
#pragma unroll
      for (int p = 0; p < 4; ++p)
        acc += dot4(wa[p], *(const float4*)(lds_x + p * 256 + lane * 4));
#pragma unroll
      for (int p = 0; p < 4; ++p)
        acc += dot4(wa[4 + p], *(const float4*)(lds_h0 + p * 256 + lane * 4));
      acc = wred(acc);
      if (lane == 0) stc8(E2p + gw, pk(__expf(acc + ab), tb + 1));
    }
    if (MODE == 1 && bid == NBLK - 1 && t > 0)
      classifier8(lds_x, lin1_w, lin1_b, lin2_w, lin2_b,
                  out + (size_t)(t - 1) * 2, lds_big);

    // ---- B: stage e [waves 0-3]; inp[j] = relu(Wx.x + (M.e)/sum(e) + b) ----
    if (wid < 4) stage8(E2p + wid * 512, lds_e + wid * 512, tb + 1, lane);
    __syncthreads();
    {
      float axh = 0.f, amh = 0.f, esh = 0.f;
#pragma unroll
      for (int p = 0; p < 2; ++p)
        axh += dot4(wxp[p], *(const float4*)(lds_x + half * 512 + p * 256 + lane * 4));
#pragma unroll
      for (int p = 0; p < 4; ++p) {
        float4 e4 = *(const float4*)(lds_e + half * 1024 + p * 256 + lane * 4);
        amh += dot4(wmp[p], e4);
        esh += e4.x + e4.y + e4.z + e4.w;
      }
      axh = wred(axh); amh = wred(amh); esh = wred(esh);
      if (lane == 0) { sb[wid * 3] = axh; sb[wid * 3 + 1] = amh; sb[wid * 3 + 2] = esh; }
    }
    __syncthreads();
    if (tid < 4) {
      float ax = sb[tid * 6] + sb[tid * 6 + 3];
      float am = sb[tid * 6 + 1] + sb[tid * 6 + 4];
      float es = sb[tid * 6 + 2] + sb[tid * 6 + 5];
      stc8(I2p + bid * 4 + tid, pk(fmaxf(ax + am / es + scb[tid], 0.f), tb + 2));
    }

    // ---- C: stage inp [waves 0-1]; LSTM layer 0 (h_prev = lds_h0) ----
    if (wid < 2) stage8(I2p + wid * 512, lds_v + wid * 512, tb + 2, lane);
    __syncthreads();
    {
      float a0 = 0.f, a1 = 0.f;
#pragma unroll
      for (int p = 0; p < 4; ++p) {
        float4 v4 = *(const float4*)(lds_v + p * 256 + lane * 4);
        float4 h4 = *(const float4*)(lds_h0 + p * 256 + lane * 4);
        a0 += dot4(wi0A[p], v4) + dot4(wh0A[p], h4);
        a1 += dot4(wi0B[p], v4) + dot4(wh0B[p], h4);
      }
      a0 = wred(a0); a1 = wred(a1);
      if (lane == 0) { sg[(wid >> 1) * 4 + gb] = a0; sg[(wid >> 1) * 4 + gb + 1] = a1; }
    }
    __syncthreads();
    if (tid < 4) {
      float gi = sg[tid * 4 + 0] + bs0[tid * 4 + 0];
      float gf = sg[tid * 4 + 1] + bs0[tid * 4 + 1];
      float gg = sg[tid * 4 + 2] + bs0[tid * 4 + 2];
      float go = sg[tid * 4 + 3] + bs0[tid * 4 + 3];
      float c = sigm(gf) * sc0[tid] + sigm(gi) * tanhf(gg);
      sc0[tid] = c;
      stc8(H2p + bid * 4 + tid, pk(sigm(go) * tanhf(c), tb + 3));
    }

    // ---- D: stage h0(t) [waves 0-1]; LSTM layer 1 (h_prev = lds_x) ----
    if (wid < 2) stage8(H2p + wid * 512, lds_h0 + wid * 512, tb + 3, lane);
    if (t == 0)   // h1(-1) = hidden[1], not x(0)=0
      *(float2*)(lds_x + tid * 2) = *(const float2*)(hidden + HD + tid * 2);
    __syncthreads();
    {
      float a0 = 0.f, a1 = 0.f;
#pragma unroll
      for (int p = 0; p < 4; ++p) {
        float4 v4 = *(const float4*)(lds_h0 + p * 256 + lane * 4);
        float4 h4 = *(const float4*)(lds_x + p * 256 + lane * 4);
        a0 += dot4(wi1A[p], v4) + dot4(wh1A[p], h4);
        a1 += dot4(wi1B[p], v4) + dot4(wh1B[p], h4);
      }
      a0 = wred(a0); a1 = wred(a1);
      if (lane == 0) { sg[(wid >> 1) * 4 + gb] = a0; sg[(wid >> 1) * 4 + gb + 1] = a1; }
    }
    __syncthreads();
    if (tid < 4) {
      float gi = sg[tid * 4 + 0] + bs1[tid * 4 + 0];
      float gf = sg[tid * 4 + 1] + bs1[tid * 4 + 1];
      float gg = sg[tid * 4 + 2] + bs1[tid * 4 + 2];
      float go = sg[tid * 4 + 3] + bs1[tid * 4 + 3];
      float c = sigm(gf) * sc1_[tid] + sigm(gi) * tanhf(gg);
      sc1_[tid] = c;
      float h1v = sigm(go) * tanhf(c);
      stc8(X2n + bid * 4 + tid, pk(h1v, tb + 4));
      if (MODE == 2) stcf(xh + (size_t)(t + 1) * HD + bid * 4 + tid, h1v);
    }
  }

  // ================= epilogue =================
  bar_arrive(bar, 2); bar_wait(bar, 2);   // all xh / final-state stores visible
  if (tid < 4) {
    out[4096 + 2 * HD + bid * 4 + tid] = sc0[tid];
    out[4096 + 3 * HD + bid * 4 + tid] = sc1_[tid];
  }
  if (bid == 0) {
    *(float2*)(out + 4096 + tid * 2) = *(const float2*)(lds_h0 + tid * 2);  // h0 final
    const u64* xf = X2;                                   // x(SD) parity = 0
    out[4096 + HD + tid]       = pv(ldc8(xf + tid));      // h1 final
    out[4096 + HD + 512 + tid] = pv(ldc8(xf + 512 + tid));
  }
  if (MODE == 2) {
    // classifier for all steps: wave -> step tt = bid*8 + wid; outs[tt] = xh[tt+1]
    const int tt = bid * 8 + wid;
    const float* xr = xh + (size_t)(tt + 1) * HD;
    float4 xv[4];
#pragma unroll
    for (int p = 0; p < 4; ++p) {
      float2 lo = ldc2(xr + p * 256 + lane * 4);
      float2 hi = ldc2(xr + p * 256 + lane * 4 + 2);
      xv[p].x = lo.x; xv[p].y = lo.y; xv[p].z = hi.x; xv[p].w = hi.y;
    }
    float* hid = lds_big + wid * 64;
#pragma unroll 2
    for (int o = 0; o < 64; ++o) {
      const float* wo = lin1_w + (size_t)o * HD;
      float acc = 0.f;
#pragma unroll
      for (int p = 0; p < 4; ++p)
        acc += dot4(*(const float4*)(wo + p * 256 + lane * 4), xv[p]);
      acc = wred(acc);
      if (lane == 0) hid[o] = fmaxf(acc + lin1_b[o], 0.f);
    }
    float hv = hid[lane];
    float r0 = wred(hv * lin2_w[lane]);
    float r1 = wred(hv * lin2_w[64 + lane]);
    if (lane == 0) {
      float l0 = r0 + lin2_b[0], l1 = r1 + lin2_b[1];
      float m = fmaxf(l0, l1);
      float e0 = __expf(l0 - m), e1 = __expf(l1 - m);
      float inv = 1.f / (e0 + e1);
      out[(size_t)tt * 2]     = e0 * inv;
      out[(size_t)tt * 2 + 1] = e1 * inv;
    }
  } else if (bid == NBLK - 1) {
    lds_x[tid]       = pv(ldc8(X2 + tid));
    lds_x[512 + tid] = pv(ldc8(X2 + 512 + tid));
    __syncthreads();
    classifier8(lds_x, lin1_w, lin1_b, lin2_w, lin2_b,
                out + (size_t)(SD - 1) * 2, lds_big);
  }
}

extern "C" void kernel_launch(void* const* d_in, const int* in_sizes, int n_in,
                              void* d_out, int out_size, void* d_ws, size_t ws_size,
                              hipStream_t stream) {
  const float* enc    = (const float*)d_in[0];
  const float* hidden = (const float*)d_in[1];
  const float* cell   = (const float*)d_in[2];
  const float* attn_w = (const float*)d_in[3];
  const float* attn_b = (const float*)d_in[4];
  const float* comb_w = (const float*)d_in[5];
  const float* comb_b = (const float*)d_in[6];
  const float* w_ih   = (const float*)d_in[7];
  const float* w_hh   = (const float*)d_in[8];
  const float* b_ih   = (const float*)d_in[9];
  const float* b_hh   = (const float*)d_in[10];
  const float* lin1_w = (const float*)d_in[11];
  const float* lin1_b = (const float*)d_in[12];
  const float* lin2_w = (const float*)d_in[13];
  const float* lin2_b = (const float*)d_in[14];
  float* out = (float*)d_out;
  float* ws  = (float*)d_ws;

  // zero flags + ALL tag buffers each launch (replay determinism; tag0 == x(0)=0)
  hipMemsetAsync(d_ws, 0, TAG_END, stream);
  if (ws_size >= WS_NEED_XH) {
    decoder_kernel<2><<<dim3(NBLK), dim3(TPB), 0, stream>>>(
        enc, attn_w, attn_b, comb_w, comb_b, w_ih, w_hh, b_ih, b_hh,
        lin1_w, lin1_b, lin2_w, lin2_b, hidden, cell, out, ws);
  } else {
    decoder_kernel<1><<<dim3(NBLK), dim3(TPB), 0, stream>>>(
        enc, attn_w, attn_b, comb_w, comb_b, w_ih, w_hh, b_ih, b_hh,
        lin1_w, lin1_b, lin2_w, lin2_b, hidden, cell, out, ws);
  }
  (void)in_sizes; (void)n_in; (void)out_size;
}